// Round 7
// baseline (136.407 us; speedup 1.0000x reference)
//
#include <hip/hip_runtime.h>
#include <cmath>
#include <algorithm>
#include <cstdint>

#ifndef M_PI
#define M_PI 3.14159265358979323846
#endif

// Problem constants (fixed by setup_inputs in the reference)
#define B_ 8
#define F_ 3
#define H_ 224
#define W_ 224
#define T_ 8          // ntau
#define A_ 12         // num_angles
#define NK 96         // T_*A_
#define HS_ 112
#define WS_ 112
#define PLANE_ (H_ * W_)        // 50176
#define SLICE_ (HS_ * WS_)      // 12544

// R7: eliminate the staging ds_write soup.
// Evidence: kernel time (34.9-35.5 us) is invariant to bank conflicts,
// staging volume, store contiguity/width, and wave-iter count. The shared
// cost across all LDS variants: 17K-23K scattered ds_write_b32 per block
// repacking global->LDS (the per-CU LDS pipe serializes ALL ds ops from
// 4 SIMDs x 2 blocks). Fix:
//   1) pre-pass kernel writes a 4-phase-permuted input copy to d_ws
//      (row = [P0[56]|P1[56]|P2[56]|P3[56]], phase p holds col 4u+p);
//   2) main kernel stages its row-band as a PURE LINEAR copy via
//      __builtin_amdgcn_global_load_lds width 16 (linear dest == builtin's
//      constraint, permutation already done global-side) — zero ds_writes;
//   3) compute = R6's conflict-free 4-phase scheme (full-row tasks,
//      4x ds_read2_b32 offset1:224, dwordx2 stores).
// Guard: ws_size < 4.82 MB -> R6 fallback kernel (correct either way).
#define RI 8          // output rows per block
#define BANDROWS 78   // 2*(RI-1) + group cy-range (59) + 2 = 75 (<=78)
#define NLANE 56      // active lanes per full-row task
#define PH4 56        // phase length (dwords)
#define PITCH4 224    // dense row pitch = 4*PH4 (both in P and in LDS)

struct LPArgs {
    int   cy[NK];  int cx[NK];
    float fy[NK];  float fx[NK];
    int   korig[NK];
    int   cymin[2]; int cymax[2];
};

static LPArgs make_args() {
    int cy[NK], cx[NK]; float fy[NK], fx[NK];
    double c = pow(60.0, 1.0 / 7.0) - 1.0;
    for (int t = 0; t < T_; ++t) {
        double tau = pow(1.0 + c, (double)t);
        for (int a = 0; a < A_; ++a) {
            double th = (double)a * (2.0 * M_PI / (double)A_) - M_PI;
            float yo = (float)(tau * sin(th)), xo = (float)(tau * cos(th));
            int k = t * A_ + a;
            float yf = floorf(yo), xf = floorf(xo);
            cy[k] = (int)yf; fy[k] = yo - yf;
            cx[k] = (int)xf; fx[k] = xo - xf;
        }
    }
    int idx[NK];
    for (int k = 0; k < NK; ++k) idx[k] = k;
    std::sort(idx, idx + NK, [&](int a, int b) { return cy[a] < cy[b]; });
    LPArgs r;
    r.cymin[0] = r.cymin[1] = 1000; r.cymax[0] = r.cymax[1] = -1000;
    for (int p = 0; p < NK; ++p) {
        int k = idx[p], g = p / 48;
        r.cy[p] = cy[k]; r.cx[p] = cx[k];
        r.fy[p] = fy[k]; r.fx[p] = fx[k];
        r.korig[p] = k;
        r.cymin[g] = std::min(r.cymin[g], cy[k]);
        r.cymax[g] = std::max(r.cymax[g], cy[k]);
    }
    return r;
}

// ---- async global->LDS (wave-uniform LDS base + lane*16; per-lane gsrc) ----
typedef __attribute__((address_space(3))) unsigned int       lds_u32;
typedef __attribute__((address_space(1))) const unsigned int glb_u32;
static __device__ __forceinline__ void async_copy16(const void* g, void* l) {
    __builtin_amdgcn_global_load_lds((glb_u32*)g, (lds_u32*)l, 16, 0, 0);
}

// ---- pre-pass: permute input into 4-phase layout in workspace ----
// P[bfr][p][u] = inp[bfr][4u+p]; quad q <-> (bfr = q/56, u = q%56).
// Reads: perfectly coalesced float4. Writes: 4 contiguous 224 B streams/wave.
__global__ __launch_bounds__(256) void lp_permute_kernel(
    const float* __restrict__ inp, float* __restrict__ P) {
    const int q = (int)blockIdx.x * 256 + (int)threadIdx.x;  // 0..301055
    const float4 v = ((const float4*)inp)[q];
    const int bfr = q / PH4;             // plane-row index (24*224)
    const int u   = q - bfr * PH4;
    float* row = P + (size_t)bfr * PITCH4;
    row[u]           = v.x;   // col 4u   (phase 0)
    row[PH4 + u]     = v.y;   // col 4u+1 (phase 1)
    row[2 * PH4 + u] = v.z;   // col 4u+2 (phase 2)
    row[3 * PH4 + u] = v.w;   // col 4u+3 (phase 3)
}

// ---- main kernel: linear async staging from P + 4-phase compute ----
// Grid (24 bf, 14 i-tiles, 2 cy-groups) = 672 blocks, 1024 threads (16 waves),
// LDS 78*224*4 = 69,888 B; launch_bounds(1024,8) -> VGPR<=64, 2 blocks/CU.
__global__ __launch_bounds__(1024, 8) void lp_main_kernel(
    const float* __restrict__ P, float* __restrict__ out, LPArgs args) {

    __shared__ float lds[BANDROWS * PITCH4];   // 69,888 B

    const int bf = blockIdx.x;            // b*F + f
    const int i0 = blockIdx.y * RI;
    const int g  = blockIdx.z;

    const int r0 = max(0, 2 * i0 + args.cymin[g]);
    const int r1 = min(H_ - 1, 2 * i0 + 2 * (RI - 1) + args.cymax[g] + 1);
    const int nrows = min(r1 - r0 + 1, BANDROWS);   // <= 75

    const int lane = threadIdx.x & 63;
    const int wave = __builtin_amdgcn_readfirstlane((int)threadIdx.x >> 6);

    // staging: rows r0..r1 of permuted plane = one contiguous span.
    const float* src = P + (size_t)bf * PLANE_ + (size_t)r0 * PITCH4;
    const int Db = nrows * (PITCH4 * 4);  // bytes, multiple of 896
    const int C  = Db >> 10;              // full 1024 B wave-chunks (<=65)
    for (int c = wave; c < C; c += 16)    // zero ds_write instructions
        async_copy16(src + c * 256 + lane * 4, (char*)lds + (c << 10));
    const int tail4 = (Db - (C << 10)) >> 4;        // <64 float4s
    for (int t = threadIdx.x; t < tail4; t += 1024)
        ((float4*)lds)[(C << 6) + t] = ((const float4*)src)[(C << 6) + t];
    __syncthreads();                      // drains vmcnt (incl. load_lds)

    float* outp = out + (size_t)bf * (NK * SLICE_) + (size_t)i0 * WS_;
    const bool act = (lane < NLANE);

#pragma unroll 1
    for (int tt = 0; tt < 3; ++tt) {
        const int kk = g * 48 + wave + (tt << 4);     // sorted slot, 0..95

        const int   cy = args.cy[kk]; const float fy = args.fy[kk];
        const int   cx = args.cx[kk]; const float fx = args.fx[kk];
        const int   ko = args.korig[kk];
        const float omfx = 1.0f - fx;

        // lane l -> out cols {2l,2l+1}; taps = cols 4l+cx+t, t=0..3.
        // col c lives at phase c&3, index c>>2; with s=cx+t (uniform):
        // phase = s&3 (uniform), index = l + (s>>2) (lane-stride-1 -> no
        // bank conflicts; 56 lanes over 32 banks = 2-way = free, m136).
        const int l = lane;
        const float* tp[4];
        float tw[4];
#pragma unroll
        for (int t = 0; t < 4; ++t) {
            const int s  = cx + t;
            const int ct = 4 * l + s;                 // tap column
            const int ph = s & 3;
            int idx = l + (s >> 2);                   // arith shift ok (s<0)
            idx = min(max(idx, 0), PH4 - 1);          // weight 0 when clamped
            tp[t] = lds + ph * PH4 + idx;
            tw[t] = (ct >= 0 && ct < W_) ? ((t & 1) ? fx : omfx) : 0.0f;
        }

        float2* orow = (float2*)(outp + (size_t)ko * SLICE_) + l;

        if (act) {
#pragma unroll 2
            for (int di = 0; di < RI; ++di) {
                const int iy0 = 2 * (i0 + di) + cy;   // wave-uniform
                float mA, mB;
                if (iy0 >= 0 && iy0 <= H_ - 2)  { mA = 1.0f - fy; mB = fy; }
                else if (iy0 == -1)             { mA = fy;        mB = 0.0f; }
                else if (iy0 == H_ - 1)         { mA = 0.0f;      mB = 1.0f - fy; }
                else                            { mA = 0.0f;      mB = 0.0f; }
                const int by = min(max(iy0, 0), H_ - 2);
                const int rb = min(by - r0, BANDROWS - 2) * PITCH4;

                // 4x ds_read2_b32 offset0:0 offset1:224 (conflict-free)
                const float a0 = tp[0][rb], a1 = tp[0][rb + PITCH4];
                const float b0 = tp[1][rb], b1 = tp[1][rb + PITCH4];
                const float c0 = tp[2][rb], c1 = tp[2][rb + PITCH4];
                const float d0 = tp[3][rb], d1 = tp[3][rb + PITCH4];

                float2 rr;
                rr.x = mA * (tw[0] * a0 + tw[1] * b0)
                     + mB * (tw[0] * a1 + tw[1] * b1);
                rr.y = mA * (tw[2] * c0 + tw[3] * d0)
                     + mB * (tw[2] * c1 + tw[3] * d1);

                orow[(size_t)di * (WS_ / 2)] = rr;    // dwordx2 store
            }
        }
    }
}

// ---- fallback (R6 verbatim, measured 35.5 us): used if ws too small ----
#define FPH 57
#define FPITCH 228
__global__ __launch_bounds__(1024, 8) void lp_fallback_kernel(
    const float* __restrict__ inp, float* __restrict__ out, LPArgs args) {

    __shared__ float lds[BANDROWS * FPITCH];

    const int bf = blockIdx.x;
    const int i0 = blockIdx.y * RI;
    const int g  = blockIdx.z;

    const int r0 = max(0, 2 * i0 + args.cymin[g]);
    const int r1 = min(H_ - 1, 2 * i0 + 2 * (RI - 1) + args.cymax[g] + 1);
    const int nrows = min(r1 - r0 + 1, BANDROWS);

    const float* plane = inp + (size_t)bf * PLANE_;
    {
        const int n = nrows * (W_ / 4);
        for (int v = threadIdx.x; v < n; v += 1024) {
            const unsigned r = (unsigned)v / 56u;
            const int u = v - (int)r * 56;
            const float4 val = *(const float4*)(plane + (size_t)(r0 + (int)r) * W_ + 4 * u);
            float* rowp = lds + r * FPITCH + u;
            rowp[0 * FPH] = val.x; rowp[1 * FPH] = val.y;
            rowp[2 * FPH] = val.z; rowp[3 * FPH] = val.w;
        }
    }
    __syncthreads();

    const int lane = threadIdx.x & 63;
    const int wave = __builtin_amdgcn_readfirstlane((int)threadIdx.x >> 6);
    float* outp = out + (size_t)bf * (NK * SLICE_) + (size_t)i0 * WS_;
    const bool act = (lane < NLANE);

#pragma unroll 1
    for (int tt = 0; tt < 3; ++tt) {
        const int kk = g * 48 + wave + (tt << 4);
        const int   cy = args.cy[kk]; const float fy = args.fy[kk];
        const int   cx = args.cx[kk]; const float fx = args.fx[kk];
        const int   ko = args.korig[kk];
        const float omfx = 1.0f - fx;
        const int l = lane;
        const float* tp[4]; float tw[4];
#pragma unroll
        for (int t = 0; t < 4; ++t) {
            const int s = cx + t; const int ct = 4 * l + s; const int ph = s & 3;
            int idx = l + (s >> 2);
            idx = min(max(idx, 0), NLANE - 1);
            tp[t] = lds + ph * FPH + idx;
            tw[t] = (ct >= 0 && ct < W_) ? ((t & 1) ? fx : omfx) : 0.0f;
        }
        float2* orow = (float2*)(outp + (size_t)ko * SLICE_) + l;
        if (act) {
#pragma unroll 2
            for (int di = 0; di < RI; ++di) {
                const int iy0 = 2 * (i0 + di) + cy;
                float mA, mB;
                if (iy0 >= 0 && iy0 <= H_ - 2)  { mA = 1.0f - fy; mB = fy; }
                else if (iy0 == -1)             { mA = fy;        mB = 0.0f; }
                else if (iy0 == H_ - 1)         { mA = 0.0f;      mB = 1.0f - fy; }
                else                            { mA = 0.0f;      mB = 0.0f; }
                const int by = min(max(iy0, 0), H_ - 2);
                const int rb = min(by - r0, BANDROWS - 2) * FPITCH;
                const float a0 = tp[0][rb], a1 = tp[0][rb + FPITCH];
                const float b0 = tp[1][rb], b1 = tp[1][rb + FPITCH];
                const float c0 = tp[2][rb], c1 = tp[2][rb + FPITCH];
                const float d0 = tp[3][rb], d1 = tp[3][rb + FPITCH];
                float2 rr;
                rr.x = mA * (tw[0] * a0 + tw[1] * b0) + mB * (tw[0] * a1 + tw[1] * b1);
                rr.y = mA * (tw[2] * c0 + tw[3] * d0) + mB * (tw[2] * c1 + tw[3] * d1);
                orow[(size_t)di * (WS_ / 2)] = rr;
            }
        }
    }
}

extern "C" void kernel_launch(void* const* d_in, const int* in_sizes, int n_in,
                              void* d_out, int out_size, void* d_ws, size_t ws_size,
                              hipStream_t stream) {
    const float* inp = (const float*)d_in[0];
    float*       out = (float*)d_out;

    static const LPArgs args = make_args();   // host-side, once; capture-safe

    const size_t needP = (size_t)B_ * F_ * PLANE_ * sizeof(float);  // 4.82 MB
    if (d_ws != nullptr && ws_size >= needP) {
        float* P = (float*)d_ws;
        lp_permute_kernel<<<dim3((B_ * F_ * PLANE_ / 4) / 256), 256, 0, stream>>>(inp, P);
        lp_main_kernel<<<dim3(B_ * F_, HS_ / RI, 2), 1024, 0, stream>>>(P, out, args);
    } else {
        lp_fallback_kernel<<<dim3(B_ * F_, HS_ / RI, 2), 1024, 0, stream>>>(inp, out, args);
    }
}